// Round 15
// baseline (2056.585 us; speedup 1.0000x reference)
//
#include <hip/hip_runtime.h>
#include <cstdint>
#include <cstddef>

#define SEQ   256
#define INP   4
#define BOND  128
#define BATCH 2048
#define MATSZ (BOND*BOND)

typedef __bf16 bf16x8 __attribute__((ext_vector_type(8)));
typedef __bf16 bf16x4 __attribute__((ext_vector_type(4)));
typedef float  f32x4  __attribute__((ext_vector_type(4)));
typedef short  s16x4  __attribute__((ext_vector_type(4)));

// ---- workspace layout (bytes) ----
static constexpr size_t SZ_MAT   = (size_t)SEQ*INP*MATSZ*2;   // 32 MiB each
static constexpr size_t OFF_ABF  = 0;
static constexpr size_t OFF_ATBF = OFF_ABF + SZ_MAT;
static constexpr size_t OFF_BHI  = OFF_ATBF + SZ_MAT;
static constexpr size_t OFF_BLO  = OFF_BHI + SZ_MAT;
static constexpr size_t SZ_MWS   = 2ull*MATSZ*2;              // 2 chains final M (bf16, linear)
static constexpr size_t SZ_TAIL  = SZ_MWS + (size_t)BATCH*4 + 64;

static __device__ __forceinline__ unsigned short f2bf(float f) {
    union { float f; uint32_t u; } v; v.f = f;
    uint32_t r = (v.u + 0x7FFFu + ((v.u >> 16) & 1u)) >> 16;   // RNE
    return (unsigned short)r;
}
static __device__ __forceinline__ float bf2f(unsigned short b) {
    union { uint32_t u; float f; } v; v.u = ((uint32_t)b) << 16;
    return v.f;
}
static __device__ __forceinline__ f32x4 mfma16(bf16x8 a, bf16x8 b, f32x4 c) {
    return __builtin_amdgcn_mfma_f32_16x16x32_bf16(a, b, c, 0, 0, 0);
}
#if defined(__has_builtin)
#if __has_builtin(__builtin_amdgcn_mfma_f32_16x16x16bf16_1k)
#define HAVE_MFMA16X16_BUILTIN 1
#endif
#endif
static __device__ __forceinline__ f32x4 mfma16x16(bf16x4 a, bf16x4 b, f32x4 c) {
#ifdef HAVE_MFMA16X16_BUILTIN
    return __builtin_amdgcn_mfma_f32_16x16x16bf16_1k(
        __builtin_bit_cast(s16x4, a), __builtin_bit_cast(s16x4, b), c, 0, 0, 0);
#else
    asm("v_mfma_f32_16x16x16_bf16 %0, %1, %2, %0" : "+v"(c) : "v"(a), "v"(b));
    return c;
#endif
}
static __device__ __forceinline__ unsigned int cvtpk(float a, float b) {
    unsigned int d;
    asm("v_cvt_pk_bf16_f32 %0, %1, %2" : "=v"(d) : "v"(a), "v"(b));
    return d;   // lo16 = bf16(a), hi16 = bf16(b)
}
// XOR-swizzled LDS layout: 16B chunk (r, c8) at slot r*16 + (c8 ^ (r&15)).
static __device__ __forceinline__ int xoff(int r, int c8) {
    return ((r << 4) + (c8 ^ (r & 15))) << 3;
}
static __device__ __forceinline__ void gload_lds16(const unsigned short* g, unsigned short* l) {
    __builtin_amdgcn_global_load_lds((const __attribute__((address_space(1))) unsigned int*)g,
                                     (__attribute__((address_space(3))) unsigned int*)l,
                                     16, 0, 0);
}
// stage one 128x128 bf16 matrix into XOR-swizzled LDS (all 512 threads, 4 vmem/wave)
static __device__ __forceinline__ void stage_mat(const unsigned short* __restrict__ Ai,
                                                 unsigned short* dst, int tid) {
#pragma unroll
    for (int j = 0; j < 4; ++j) {
        int slot = j * 512 + tid;
        int r = slot >> 4, c8 = slot & 15;
        const unsigned short* src = Ai + (size_t)r * BOND + ((c8 ^ (r & 15)) << 3);
        unsigned short* ldst = dst + (size_t)(j * 512 + (tid & ~63)) * 8;
        gload_lds16(src, ldst);
    }
}

// ---------------- convert (unchanged) ----------------
__global__ void convert_kernel(const float* __restrict__ core,
                               unsigned short* __restrict__ abf,
                               unsigned short* __restrict__ atbf,
                               unsigned short* __restrict__ bhi,
                               unsigned short* __restrict__ blo,
                               int use_blo) {
    __shared__ unsigned short tile[BOND][BOND + 2];
    const int mat = blockIdx.x;
    const float* src = core + (size_t)mat * MATSZ;
    unsigned short* dA = abf  + (size_t)mat * MATSZ;
    unsigned short* dT = atbf + (size_t)mat * MATSZ;
    unsigned short* dH = bhi  + (size_t)mat * MATSZ;
    unsigned short* dL = blo  + (size_t)mat * MATSZ;
    const int tid = threadIdx.x;
    for (int j = 0; j < 16; ++j) {
        int lin4 = (tid + j * 256) * 4;
        float4 f = *(const float4*)(src + lin4);
        int r = lin4 >> 7, c = lin4 & 127;
        unsigned short a0=f2bf(f.x), a1=f2bf(f.y), a2=f2bf(f.z), a3=f2bf(f.w);
        *(ushort4*)(dA + lin4) = make_ushort4(a0,a1,a2,a3);
        tile[r][c]=a0; tile[r][c+1]=a1; tile[r][c+2]=a2; tile[r][c+3]=a3;
        float b0 = f.x - ((r == c    ) ? 1.0f : 0.0f);
        float b1 = f.y - ((r == c + 1) ? 1.0f : 0.0f);
        float b2 = f.z - ((r == c + 2) ? 1.0f : 0.0f);
        float b3 = f.w - ((r == c + 3) ? 1.0f : 0.0f);
        unsigned short h0=f2bf(b0), h1=f2bf(b1), h2=f2bf(b2), h3=f2bf(b3);
        *(ushort4*)(dH + lin4) = make_ushort4(h0,h1,h2,h3);
        if (use_blo) {
            *(ushort4*)(dL + lin4) = make_ushort4(
                f2bf(b0 - bf2f(h0)), f2bf(b1 - bf2f(h1)),
                f2bf(b2 - bf2f(h2)), f2bf(b3 - bf2f(h3)));
        }
    }
    __syncthreads();
    for (int j = 0; j < 16; ++j) {
        int lin4 = (tid + j * 256) * 4;
        int co = lin4 >> 7, r0 = lin4 & 127;
        *(ushort4*)(dT + lin4) = make_ushort4(tile[r0][co], tile[r0+1][co],
                                              tile[r0+2][co], tile[r0+3][co]);
    }
}

// ---------------- merged main kernel: blocks 0..1 = Z (4-buffer, counted vmcnt),
// ---------------- blocks 2..129 = amplitude (16 cols/block, r14-proven) ----------------
struct ZSm {
    unsigned short As[4][MATSZ];    // 128 KB quad-buffered A_i, XOR layout
    unsigned short M[MATSZ];        // 32 KB density matrix, XOR layout
};                                   // = exactly 160 KiB
struct ASm2 {
    int   toks[SEQ * 16];           // 16 KB
    unsigned short hhi[16 * BOND];  // 4 KB, XOR layout
    unsigned short hlo[16 * BOND];  // 4 KB, XOR layout
    float partial[8][16];
    float sinv[16];
    float logn[16];
};
union SmU { ZSm z; ASm2 a; };       // 160 KiB

template<int USE_BLO>
__global__ __launch_bounds__(512)
__attribute__((amdgpu_waves_per_eu(2, 2)))
void main_kernel(
        const int*   __restrict__ xdata,
        const float* __restrict__ edge,
        const unsigned short* __restrict__ abf,
        const unsigned short* __restrict__ atbf,
        const unsigned short* __restrict__ bhi,
        const unsigned short* __restrict__ blo,
        unsigned short* __restrict__ mws,
        float* __restrict__ logamp) {
    __shared__ SmU sm;
    const int tid = threadIdx.x;
    const int l   = tid & 63;
    const int w   = tid >> 6;          // wave 0..7
    const int lo  = l & 15;
    const int hi  = l >> 4;            // 0..3

    if (blockIdx.x < 2) {
        // ===== Z chain: r14 schedule + 4-buffer / 3-ahead staging + counted vmcnt =====
        // Invariant at top of iteration (token g): pb0=buf(g), pb1=buf(g+1) [complete],
        // pb2=buf(g+2) [in flight or complete], pb3=free (stage target for g+3).
        // Token barrier waits vmcnt(4): completes stages g+1,g+2; g+3 stays in flight.
        const int chain = blockIdx.x;  // 0 = fwd (alpha), 1 = bwd (omega, A^T)
        const unsigned short* Abase = chain ? atbf : abf;
        const float* ev = edge + chain * BOND;

        auto tokptr = [&](int g) -> const unsigned short* {
            int ts = chain ? (SEQ - 1 - (g >> 2)) : (g >> 2);
            return Abase + ((size_t)ts * INP + (g & 3)) * MATSZ;
        };

        // M0 = vec vec^T directly from edge (no LDS vec; one-time cost)
        for (int idx = tid; idx < MATSZ; idx += 512) {
            int r = idx >> 7, c = idx & 127;
            sm.z.M[xoff(r, c >> 3) + (c & 7)] = f2bf(ev[r] * ev[c]);
        }
        unsigned short *pb0 = sm.z.As[0], *pb1 = sm.z.As[1],
                       *pb2 = sm.z.As[2], *pb3 = sm.z.As[3];
        stage_mat(tokptr(0), pb0, tid);
        stage_mat(tokptr(1), pb1, tid);
        stage_mat(tokptr(2), pb2, tid);
        __syncthreads();               // M0 + tok0..2 ready (full drain, once)

        f32x4 accM[2][8];
        bf16x4 tf[2][8];

        auto P1 = [&](const unsigned short* Ac) {
            f32x4 acc1[8][2];
#pragma unroll
            for (int pt = 0; pt < 8; ++pt) {
                acc1[pt][0] = (f32x4){0.f, 0.f, 0.f, 0.f};
                acc1[pt][1] = (f32x4){0.f, 0.f, 0.f, 0.f};
            }
#pragma unroll
            for (int kk = 0; kk < 4; ++kk) {
                bf16x8 bq0 = *(const bf16x8*)&Ac[xoff(w * 32 + lo,      kk * 4 + hi)];
                bf16x8 bq1 = *(const bf16x8*)&Ac[xoff(w * 32 + 16 + lo, kk * 4 + hi)];
#pragma unroll
                for (int pt = 0; pt < 8; ++pt) {
                    bf16x8 mf = *(const bf16x8*)&sm.z.M[xoff(pt * 16 + lo, kk * 4 + hi)];
                    acc1[pt][0] = mfma16(mf, bq0, acc1[pt][0]);
                    acc1[pt][1] = mfma16(mf, bq1, acc1[pt][1]);
                }
            }
#pragma unroll
            for (int pt = 0; pt < 8; ++pt)
#pragma unroll
                for (int mt = 0; mt < 2; ++mt) {
                    union { unsigned int u[2]; bf16x4 v; } pk;
                    pk.u[0] = cvtpk(acc1[pt][mt][0], acc1[pt][mt][1]);
                    pk.u[1] = cvtpk(acc1[pt][mt][2], acc1[pt][mt][3]);
                    tf[mt][pt] = pk.v;
                }
        };
        auto P2 = [&](const unsigned short* Ac) {
#pragma unroll
            for (int ks = 0; ks < 8; ++ks) {
#pragma unroll
                for (int ct = 0; ct < 8; ++ct) {
                    bf16x4 bb = *(const bf16x4*)&Ac[xoff(ct * 16 + lo, 2 * ks + (hi >> 1)) + 4 * (hi & 1)];
                    accM[0][ct] = mfma16x16(tf[0][ks], bb, accM[0][ct]);
                    accM[1][ct] = mfma16x16(tf[1][ks], bb, accM[1][ct]);
                }
            }
        };

        if (w < 4) P1(pb0);            // T(token 0) from M0

        for (int s = 1; s <= 128; ++s) {
#pragma unroll
            for (int mt = 0; mt < 2; ++mt)
#pragma unroll
                for (int ct = 0; ct < 8; ++ct) accM[mt][ct] = (f32x4){0.f, 0.f, 0.f, 0.f};

            for (int i = 0; i < 4; ++i) {
                const int g = (s - 1) * 4 + i;
                if (g + 3 < 512) stage_mat(tokptr(g + 3), pb3, tid);
                if (w < 4) {
                    __builtin_amdgcn_s_setprio(1);
                    P2(pb0);                       // token g (tf from previous P1)
                    if (i < 3) P1(pb1);            // token g+1 (complete by invariant)
                    __builtin_amdgcn_s_setprio(0);
                }
                // counted wait: complete stages g+1, g+2; keep g+3 in flight (T4)
                if (g + 3 < 512) {
                    asm volatile("s_waitcnt vmcnt(4)" ::: "memory");
                } else {
                    asm volatile("s_waitcnt vmcnt(0)" ::: "memory");
                }
                __builtin_amdgcn_s_barrier();
                unsigned short* tpp = pb0; pb0 = pb1; pb1 = pb2; pb2 = pb3; pb3 = tpp;
            }
            // step end: write M' (scaled 1/4)
            if (w < 4) {
#pragma unroll
                for (int mt = 0; mt < 2; ++mt)
#pragma unroll
                    for (int ct = 0; ct < 8; ++ct)
#pragma unroll
                        for (int r = 0; r < 4; ++r) {
                            int row = w * 32 + mt * 16 + hi * 4 + r;
                            int col = ct * 16 + lo;
                            sm.z.M[xoff(row, col >> 3) + (col & 7)] =
                                f2bf(accM[mt][ct][r] * 0.25f);
                        }
            }
            asm volatile("s_waitcnt lgkmcnt(0)" ::: "memory");
            __builtin_amdgcn_s_barrier();
            if (s < 128 && w < 4) P1(pb0);         // first token of next step, new M
        }
        unsigned short* outb = mws + (size_t)chain * MATSZ;
        for (int j = 0; j < 4; ++j) {
            int chunk = tid + j * 512;
            int r = chunk >> 4, c8 = chunk & 15;
            *(bf16x8*)(outb + (size_t)r * BOND + c8 * 8) =
                *(const bf16x8*)&sm.z.M[xoff(r, c8)];
        }
    } else {
        // ===== amplitude scan: r14-proven body, 16 batch-cols per block =====
        const int lr = lo, lq = hi;
        const int b0 = (blockIdx.x - 2) * 16;

        for (int j = 0; j < 8; ++j) {
            int idx = tid + j * 512;                  // 4096 tokens
            int t = idx >> 4, c = idx & 15;
            sm.a.toks[idx] = xdata[(size_t)t * BATCH + b0 + c];
        }
        if (tid < 16) sm.a.logn[tid] = 0.f;
        for (int idx = tid; idx < 16 * BOND; idx += 512) {
            int c = idx >> 7, r = idx & 127;
            float v = edge[r];
            unsigned short hb = f2bf(v);
            int si = xoff(c, r >> 3) + (r & 7);
            sm.a.hhi[si] = hb;
            sm.a.hlo[si] = f2bf(v - bf2f(hb));
        }
        f32x4 al = *(const f32x4*)(edge + w * 16 + lq * 4);
        f32x4 hreg0 = al;
        __syncthreads();

        const size_t ro = (size_t)(w * 16 + lr) * BOND + lq * 8;

        bf16x8 bvh[4][4], bvl[4][4];
#pragma unroll
        for (int v = 0; v < 4; ++v)
#pragma unroll
            for (int kk = 0; kk < 4; ++kk) {
                bvh[v][kk] = *(const bf16x8*)(bhi + (size_t)v * MATSZ + ro + kk * 32);
                if (USE_BLO) bvl[v][kk] = *(const bf16x8*)(blo + (size_t)v * MATSZ + ro + kk * 32);
            }

        for (int t = 0; t < SEQ; ++t) {
            bf16x8 hh0[4], hl0[4];
#pragma unroll
            for (int kk = 0; kk < 4; ++kk) {
                hh0[kk] = *(const bf16x8*)&sm.a.hhi[xoff(lr, kk * 4 + lq)];
                hl0[kk] = *(const bf16x8*)&sm.a.hlo[xoff(lr, kk * 4 + lq)];
            }
            f32x4 acc[4];
#pragma unroll
            for (int v = 0; v < 4; ++v) acc[v] = (f32x4){0.f, 0.f, 0.f, 0.f};
            const unsigned short* BhN = bhi + (size_t)(t + 1) * INP * MATSZ + ro;
            const unsigned short* BlN = blo + (size_t)(t + 1) * INP * MATSZ + ro;
#pragma unroll
            for (int v = 0; v < 4; ++v) {
#pragma unroll
                for (int kk = 0; kk < 4; ++kk) {
                    acc[v] = mfma16(bvh[v][kk], hh0[kk], acc[v]);
                    acc[v] = mfma16(bvh[v][kk], hl0[kk], acc[v]);
                    if (USE_BLO) acc[v] = mfma16(bvl[v][kk], hh0[kk], acc[v]);
                }
                if (t < SEQ - 1) {
#pragma unroll
                    for (int kk = 0; kk < 4; ++kk) {
                        bvh[v][kk] = *(const bf16x8*)(BhN + (size_t)v * MATSZ + kk * 32);
                        if (USE_BLO) bvl[v][kk] = *(const bf16x8*)(BlN + (size_t)v * MATSZ + kk * 32);
                    }
                }
            }
            int tokA = sm.a.toks[t * 16 + lr];
            f32x4 d0 = acc[0];
            d0 = (tokA == 1) ? acc[1] : d0;
            d0 = (tokA == 2) ? acc[2] : d0;
            d0 = (tokA == 3) ? acc[3] : d0;
            f32x4 h2_0 = hreg0 + d0;

            if ((t & 7) == 7) {            // renormalize every 8 steps
                float ss0 = h2_0[0]*h2_0[0] + h2_0[1]*h2_0[1] + h2_0[2]*h2_0[2] + h2_0[3]*h2_0[3];
                ss0 += __shfl_xor(ss0, 16);
                ss0 += __shfl_xor(ss0, 32);
                if (lq == 0) sm.a.partial[w][lr] = ss0;
                __syncthreads();
                if (tid < 16) {
                    float s2 = 0.f;
#pragma unroll
                    for (int w2 = 0; w2 < 8; ++w2) s2 += sm.a.partial[w2][tid];
                    sm.a.sinv[tid] = rsqrtf(s2);
                    sm.a.logn[tid] += 0.5f * logf(s2);
                }
                __syncthreads();
                h2_0 *= sm.a.sinv[lr];
            }
            hreg0 = h2_0;
            __syncthreads();               // all waves' h-frag reads complete
            {
                int c = lr;
                unsigned short q0 = f2bf(h2_0[0]), q1 = f2bf(h2_0[1]),
                               q2 = f2bf(h2_0[2]), q3 = f2bf(h2_0[3]);
                int c8w = w * 2 + (lq >> 1);
                int si  = xoff(c, c8w) + (lq & 1) * 4;
                *(ushort4*)&sm.a.hhi[si] = make_ushort4(q0, q1, q2, q3);
                *(ushort4*)&sm.a.hlo[si] =
                    make_ushort4(f2bf(h2_0[0] - bf2f(q0)), f2bf(h2_0[1] - bf2f(q1)),
                                 f2bf(h2_0[2] - bf2f(q2)), f2bf(h2_0[3] - bf2f(q3)));
            }
            __syncthreads();               // writes visible before next step's reads
        }
        f32x4 og = *(const f32x4*)(edge + BOND + w * 16 + lq * 4);
        {
            float ss = hreg0[0]*og[0] + hreg0[1]*og[1] + hreg0[2]*og[2] + hreg0[3]*og[3];
            ss += __shfl_xor(ss, 16);
            ss += __shfl_xor(ss, 32);
            if (lq == 0) sm.a.partial[w][lr] = ss;
        }
        __syncthreads();
        if (tid < 16) {
            float dot = 0.f;
#pragma unroll
            for (int w2 = 0; w2 < 8; ++w2) dot += sm.a.partial[w2][tid];
            logamp[b0 + tid] = 2.f * (logf(fabsf(dot)) + sm.a.logn[tid]);
        }
    }
}

// ---------------- finalize (unchanged) ----------------
__global__ __launch_bounds__(1024) void fin_kernel(const unsigned short* __restrict__ mws,
                                                   const float* __restrict__ logamp,
                                                   float* __restrict__ out) {
    __shared__ float red[1024];
    const int tid = threadIdx.x;
    const unsigned short* Sf = mws;
    const unsigned short* Rb = mws + MATSZ;
    float part = 0.f;
    for (int j = 0; j < 16; ++j) {
        int idx = tid + j * 1024;
        part += bf2f(Sf[idx]) * bf2f(Rb[idx]);
    }
    red[tid] = part;
    __syncthreads();
    for (int off = 512; off > 0; off >>= 1) {
        if (tid < off) red[tid] += red[tid + off];
        __syncthreads();
    }
    float lz = logf(red[0]) + 256.0f * 1.3862943611198906f;
    out[tid]        = logamp[tid]        - lz;
    out[tid + 1024] = logamp[tid + 1024] - lz;
}

extern "C" void kernel_launch(void* const* d_in, const int* in_sizes, int n_in,
                              void* d_out, int out_size, void* d_ws, size_t ws_size,
                              hipStream_t stream) {
    const int*   xdata = (const int*)d_in[0];
    const float* core  = (const float*)d_in[1];
    const float* edge  = (const float*)d_in[2];
    float* out = (float*)d_out;
    char* ws = (char*)d_ws;

    const size_t need_full  = OFF_BLO + SZ_MAT + SZ_TAIL;
    const size_t need_noblo = OFF_BLO + SZ_TAIL;
    const int use_blo = (ws_size >= need_full) ? 1 : 0;
    if (!use_blo && ws_size < need_noblo) return;

    unsigned short* abf  = (unsigned short*)(ws + OFF_ABF);
    unsigned short* atbf = (unsigned short*)(ws + OFF_ATBF);
    unsigned short* bhi  = (unsigned short*)(ws + OFF_BHI);
    unsigned short* blo  = (unsigned short*)(ws + (use_blo ? OFF_BLO : OFF_BHI));
    const size_t tail = use_blo ? (OFF_BLO + SZ_MAT) : OFF_BLO;
    unsigned short* mws  = (unsigned short*)(ws + tail);
    float* logamp = (float*)(ws + tail + SZ_MWS);

    convert_kernel<<<SEQ * INP, 256, 0, stream>>>(core, abf, atbf, bhi, blo, use_blo);
    if (use_blo)
        main_kernel<1><<<130, 512, 0, stream>>>(xdata, edge, abf, atbf, bhi, blo, mws, logamp);
    else
        main_kernel<0><<<130, 512, 0, stream>>>(xdata, edge, abf, atbf, bhi, blo, mws, logamp);
    fin_kernel<<<1, 1024, 0, stream>>>(mws, logamp, out);
}

// Round 18
// 2048.490 us; speedup vs baseline: 1.0040x; 1.0040x over previous
//
#include <hip/hip_runtime.h>
#include <cstdint>
#include <cstddef>

#define SEQ   256
#define INP   4
#define BOND  128
#define BATCH 2048
#define MATSZ (BOND*BOND)

typedef __bf16 bf16x8 __attribute__((ext_vector_type(8)));
typedef __bf16 bf16x4 __attribute__((ext_vector_type(4)));
typedef float  f32x4  __attribute__((ext_vector_type(4)));
typedef short  s16x4  __attribute__((ext_vector_type(4)));

// ---- workspace layout (bytes) ----
static constexpr size_t SZ_MAT   = (size_t)SEQ*INP*MATSZ*2;   // 32 MiB each
static constexpr size_t OFF_ABF  = 0;
static constexpr size_t OFF_ATBF = OFF_ABF + SZ_MAT;
static constexpr size_t OFF_BHI  = OFF_ATBF + SZ_MAT;
static constexpr size_t OFF_BLO  = OFF_BHI + SZ_MAT;
static constexpr size_t SZ_MWS   = 2ull*MATSZ*2;              // 2 chains final M (bf16, linear)
static constexpr size_t SZ_TAIL  = SZ_MWS + (size_t)BATCH*4 + 64;

static __device__ __forceinline__ unsigned short f2bf(float f) {
    union { float f; uint32_t u; } v; v.f = f;
    uint32_t r = (v.u + 0x7FFFu + ((v.u >> 16) & 1u)) >> 16;   // RNE
    return (unsigned short)r;
}
static __device__ __forceinline__ float bf2f(unsigned short b) {
    union { uint32_t u; float f; } v; v.u = ((uint32_t)b) << 16;
    return v.f;
}
static __device__ __forceinline__ f32x4 mfma16(bf16x8 a, bf16x8 b, f32x4 c) {
    return __builtin_amdgcn_mfma_f32_16x16x32_bf16(a, b, c, 0, 0, 0);
}
#if defined(__has_builtin)
#if __has_builtin(__builtin_amdgcn_mfma_f32_16x16x16bf16_1k)
#define HAVE_MFMA16X16_BUILTIN 1
#endif
#endif
static __device__ __forceinline__ f32x4 mfma16x16(bf16x4 a, bf16x4 b, f32x4 c) {
#ifdef HAVE_MFMA16X16_BUILTIN
    return __builtin_amdgcn_mfma_f32_16x16x16bf16_1k(
        __builtin_bit_cast(s16x4, a), __builtin_bit_cast(s16x4, b), c, 0, 0, 0);
#else
    asm("v_mfma_f32_16x16x16_bf16 %0, %1, %2, %0" : "+v"(c) : "v"(a), "v"(b));
    return c;
#endif
}
static __device__ __forceinline__ unsigned int cvtpk(float a, float b) {
    unsigned int d;
    asm("v_cvt_pk_bf16_f32 %0, %1, %2" : "=v"(d) : "v"(a), "v"(b));
    return d;   // lo16 = bf16(a), hi16 = bf16(b)
}
// XOR-swizzled LDS layout: 16B chunk (r, c8) at slot r*16 + (c8 ^ (r&15)).
static __device__ __forceinline__ int xoff(int r, int c8) {
    return ((r << 4) + (c8 ^ (r & 15))) << 3;
}
static __device__ __forceinline__ void gload_lds16(const unsigned short* g, unsigned short* l) {
    __builtin_amdgcn_global_load_lds((const __attribute__((address_space(1))) unsigned int*)g,
                                     (__attribute__((address_space(3))) unsigned int*)l,
                                     16, 0, 0);
}
// stage one 128x128 bf16 matrix into XOR-swizzled LDS (all 512 threads)
static __device__ __forceinline__ void stage_mat(const unsigned short* __restrict__ Ai,
                                                 unsigned short* dst, int tid) {
#pragma unroll
    for (int j = 0; j < 4; ++j) {
        int slot = j * 512 + tid;
        int r = slot >> 4, c8 = slot & 15;
        const unsigned short* src = Ai + (size_t)r * BOND + ((c8 ^ (r & 15)) << 3);
        unsigned short* ldst = dst + (size_t)(j * 512 + (tid & ~63)) * 8;
        gload_lds16(src, ldst);
    }
}

// ---------------- convert (unchanged) ----------------
__global__ void convert_kernel(const float* __restrict__ core,
                               unsigned short* __restrict__ abf,
                               unsigned short* __restrict__ atbf,
                               unsigned short* __restrict__ bhi,
                               unsigned short* __restrict__ blo,
                               int use_blo) {
    __shared__ unsigned short tile[BOND][BOND + 2];
    const int mat = blockIdx.x;
    const float* src = core + (size_t)mat * MATSZ;
    unsigned short* dA = abf  + (size_t)mat * MATSZ;
    unsigned short* dT = atbf + (size_t)mat * MATSZ;
    unsigned short* dH = bhi  + (size_t)mat * MATSZ;
    unsigned short* dL = blo  + (size_t)mat * MATSZ;
    const int tid = threadIdx.x;
    for (int j = 0; j < 16; ++j) {
        int lin4 = (tid + j * 256) * 4;
        float4 f = *(const float4*)(src + lin4);
        int r = lin4 >> 7, c = lin4 & 127;
        unsigned short a0=f2bf(f.x), a1=f2bf(f.y), a2=f2bf(f.z), a3=f2bf(f.w);
        *(ushort4*)(dA + lin4) = make_ushort4(a0,a1,a2,a3);
        tile[r][c]=a0; tile[r][c+1]=a1; tile[r][c+2]=a2; tile[r][c+3]=a3;
        float b0 = f.x - ((r == c    ) ? 1.0f : 0.0f);
        float b1 = f.y - ((r == c + 1) ? 1.0f : 0.0f);
        float b2 = f.z - ((r == c + 2) ? 1.0f : 0.0f);
        float b3 = f.w - ((r == c + 3) ? 1.0f : 0.0f);
        unsigned short h0=f2bf(b0), h1=f2bf(b1), h2=f2bf(b2), h3=f2bf(b3);
        *(ushort4*)(dH + lin4) = make_ushort4(h0,h1,h2,h3);
        if (use_blo) {
            *(ushort4*)(dL + lin4) = make_ushort4(
                f2bf(b0 - bf2f(h0)), f2bf(b1 - bf2f(h1)),
                f2bf(b2 - bf2f(h2)), f2bf(b3 - bf2f(h3)));
        }
    }
    __syncthreads();
    for (int j = 0; j < 16; ++j) {
        int lin4 = (tid + j * 256) * 4;
        int co = lin4 >> 7, r0 = lin4 & 127;
        *(ushort4*)(dT + lin4) = make_ushort4(tile[r0][co], tile[r0+1][co],
                                              tile[r0+2][co], tile[r0+3][co]);
    }
}

// ---------------- merged main kernel: blocks 0..1 = Z (3-buffer lookahead),
// ---------------- blocks 2..129 = amplitude (16 cols/block) ----------------
struct ZSm {
    unsigned short As[3][MATSZ];    // 96 KB triple-buffered A_i, XOR layout
    unsigned short M[MATSZ];        // 32 KB density matrix, XOR layout
    float vec[BOND];
};
struct ASm2 {
    int   toks[SEQ * 16];           // 16 KB
    unsigned short hhi[16 * BOND];  // 4 KB, XOR layout
    unsigned short hlo[16 * BOND];  // 4 KB, XOR layout
    float partial[8][16];
    float sinv[16];
    float logn[16];
};
union SmU { ZSm z; ASm2 a; };       // 128.5 KB

template<int USE_BLO>
__global__ __launch_bounds__(512)
__attribute__((amdgpu_waves_per_eu(2, 2)))
void main_kernel(
        const int*   __restrict__ xdata,
        const float* __restrict__ edge,
        const unsigned short* __restrict__ abf,
        const unsigned short* __restrict__ atbf,
        const unsigned short* __restrict__ bhi,
        const unsigned short* __restrict__ blo,
        unsigned short* __restrict__ mws,
        float* __restrict__ logamp) {
    __shared__ SmU sm;
    const int tid = threadIdx.x;
    const int l   = tid & 63;
    const int w   = tid >> 6;          // wave 0..7
    const int lo  = l & 15;
    const int hi  = l >> 4;            // 0..3

    if (blockIdx.x < 2) {
        // ===== Z chain: r12-proven wave structure + 3-buffer token lookahead =====
        // Invariant at top of iteration for token g: pb0 = buf(g), pb1 = buf(g+1),
        // pb2 = free/staging target (token g+2); tf holds T(token g).
        const int chain = blockIdx.x;  // 0 = fwd (alpha), 1 = bwd (omega, A^T)
        const unsigned short* Abase = chain ? atbf : abf;

        auto tokptr = [&](int g) -> const unsigned short* {
            int ts = chain ? (SEQ - 1 - (g >> 2)) : (g >> 2);
            return Abase + ((size_t)ts * INP + (g & 3)) * MATSZ;
        };

        if (tid < BOND) sm.z.vec[tid] = edge[chain * BOND + tid];
        __syncthreads();
        for (int idx = tid; idx < MATSZ; idx += 512) {
            int r = idx >> 7, c = idx & 127;
            sm.z.M[xoff(r, c >> 3) + (c & 7)] = f2bf(sm.z.vec[r] * sm.z.vec[c]);
        }
        unsigned short *pb0 = sm.z.As[0], *pb1 = sm.z.As[1], *pb2 = sm.z.As[2];
        stage_mat(tokptr(0), pb0, tid);
        stage_mat(tokptr(1), pb1, tid);
        __syncthreads();               // M0 + tok0 + tok1 ready (full drain, once)

        f32x4 accM[2][8];
        bf16x4 tf[2][8];

        // P1: T(token from Ac) -> tf (in-register, swapped form C1 = M * A^T)
        auto P1 = [&](const unsigned short* Ac) {
            f32x4 acc1[8][2];
#pragma unroll
            for (int pt = 0; pt < 8; ++pt) {
                acc1[pt][0] = (f32x4){0.f, 0.f, 0.f, 0.f};
                acc1[pt][1] = (f32x4){0.f, 0.f, 0.f, 0.f};
            }
#pragma unroll
            for (int kk = 0; kk < 4; ++kk) {
                bf16x8 bq0 = *(const bf16x8*)&Ac[xoff(w * 32 + lo,      kk * 4 + hi)];
                bf16x8 bq1 = *(const bf16x8*)&Ac[xoff(w * 32 + 16 + lo, kk * 4 + hi)];
#pragma unroll
                for (int pt = 0; pt < 8; ++pt) {
                    bf16x8 mf = *(const bf16x8*)&sm.z.M[xoff(pt * 16 + lo, kk * 4 + hi)];
                    acc1[pt][0] = mfma16(mf, bq0, acc1[pt][0]);
                    acc1[pt][1] = mfma16(mf, bq1, acc1[pt][1]);
                }
            }
#pragma unroll
            for (int pt = 0; pt < 8; ++pt)
#pragma unroll
                for (int mt = 0; mt < 2; ++mt) {
                    union { unsigned int u[2]; bf16x4 v; } pk;
                    pk.u[0] = cvtpk(acc1[pt][mt][0], acc1[pt][mt][1]);
                    pk.u[1] = cvtpk(acc1[pt][mt][2], acc1[pt][mt][3]);
                    tf[mt][pt] = pk.v;
                }
        };
        // P2: accM += T * A^T (16x16x16, B = A rows, 8B reads)
        auto P2 = [&](const unsigned short* Ac) {
#pragma unroll
            for (int ks = 0; ks < 8; ++ks) {
#pragma unroll
                for (int ct = 0; ct < 8; ++ct) {
                    bf16x4 bb = *(const bf16x4*)&Ac[xoff(ct * 16 + lo, 2 * ks + (hi >> 1)) + 4 * (hi & 1)];
                    accM[0][ct] = mfma16x16(tf[0][ks], bb, accM[0][ct]);
                    accM[1][ct] = mfma16x16(tf[1][ks], bb, accM[1][ct]);
                }
            }
        };

        if (w < 4) P1(pb0);            // T(token 0) from M0

        for (int s = 1; s <= 128; ++s) {
#pragma unroll
            for (int mt = 0; mt < 2; ++mt)
#pragma unroll
                for (int ct = 0; ct < 8; ++ct) accM[mt][ct] = (f32x4){0.f, 0.f, 0.f, 0.f};

            for (int i = 0; i < 4; ++i) {
                const int g = (s - 1) * 4 + i;
                if (g + 2 < 512) stage_mat(tokptr(g + 2), pb2, tid);
                if (w < 4) {
                    __builtin_amdgcn_s_setprio(1);
                    P2(pb0);                       // token g (tf from previous P1)
                    if (i < 3) P1(pb1);            // token g+1 (buffer already resident)
                    __builtin_amdgcn_s_setprio(0);
                }
                asm volatile("s_waitcnt vmcnt(0)" ::: "memory");
                __builtin_amdgcn_s_barrier();
                unsigned short* tpp = pb0; pb0 = pb1; pb1 = pb2; pb2 = tpp;
            }
            // step end: write M' (scaled 1/4)
            if (w < 4) {
#pragma unroll
                for (int mt = 0; mt < 2; ++mt)
#pragma unroll
                    for (int ct = 0; ct < 8; ++ct)
#pragma unroll
                        for (int r = 0; r < 4; ++r) {
                            int row = w * 32 + mt * 16 + hi * 4 + r;
                            int col = ct * 16 + lo;
                            sm.z.M[xoff(row, col >> 3) + (col & 7)] =
                                f2bf(accM[mt][ct][r] * 0.25f);
                        }
            }
            asm volatile("s_waitcnt lgkmcnt(0)" ::: "memory");
            __builtin_amdgcn_s_barrier();
            if (s < 128 && w < 4) P1(pb0);         // first token of next step, new M
        }
        unsigned short* outb = mws + (size_t)chain * MATSZ;
        for (int j = 0; j < 4; ++j) {
            int chunk = tid + j * 512;
            int r = chunk >> 4, c8 = chunk & 15;
            *(bf16x8*)(outb + (size_t)r * BOND + c8 * 8) =
                *(const bf16x8*)&sm.z.M[xoff(r, c8)];
        }
    } else {
        // ===== amplitude scan: r12-proven body, 16 batch-cols per block =====
        const int lr = lo, lq = hi;
        const int b0 = (blockIdx.x - 2) * 16;

        for (int j = 0; j < 8; ++j) {
            int idx = tid + j * 512;                  // 4096 tokens
            int t = idx >> 4, c = idx & 15;
            sm.a.toks[idx] = xdata[(size_t)t * BATCH + b0 + c];
        }
        if (tid < 16) sm.a.logn[tid] = 0.f;
        for (int idx = tid; idx < 16 * BOND; idx += 512) {
            int c = idx >> 7, r = idx & 127;
            float v = edge[r];
            unsigned short hb = f2bf(v);
            int si = xoff(c, r >> 3) + (r & 7);
            sm.a.hhi[si] = hb;
            sm.a.hlo[si] = f2bf(v - bf2f(hb));
        }
        f32x4 al = *(const f32x4*)(edge + w * 16 + lq * 4);
        f32x4 hreg0 = al;
        __syncthreads();

        const size_t ro = (size_t)(w * 16 + lr) * BOND + lq * 8;

        bf16x8 bvh[4][4], bvl[4][4];
#pragma unroll
        for (int v = 0; v < 4; ++v)
#pragma unroll
            for (int kk = 0; kk < 4; ++kk) {
                bvh[v][kk] = *(const bf16x8*)(bhi + (size_t)v * MATSZ + ro + kk * 32);
                if (USE_BLO) bvl[v][kk] = *(const bf16x8*)(blo + (size_t)v * MATSZ + ro + kk * 32);
            }

        for (int t = 0; t < SEQ; ++t) {
            bf16x8 hh0[4], hl0[4];
#pragma unroll
            for (int kk = 0; kk < 4; ++kk) {
                hh0[kk] = *(const bf16x8*)&sm.a.hhi[xoff(lr, kk * 4 + lq)];
                hl0[kk] = *(const bf16x8*)&sm.a.hlo[xoff(lr, kk * 4 + lq)];
            }
            f32x4 acc[4];
#pragma unroll
            for (int v = 0; v < 4; ++v) acc[v] = (f32x4){0.f, 0.f, 0.f, 0.f};
            const unsigned short* BhN = bhi + (size_t)(t + 1) * INP * MATSZ + ro;
            const unsigned short* BlN = blo + (size_t)(t + 1) * INP * MATSZ + ro;
#pragma unroll
            for (int v = 0; v < 4; ++v) {
#pragma unroll
                for (int kk = 0; kk < 4; ++kk) {
                    acc[v] = mfma16(bvh[v][kk], hh0[kk], acc[v]);
                    acc[v] = mfma16(bvh[v][kk], hl0[kk], acc[v]);
                    if (USE_BLO) acc[v] = mfma16(bvl[v][kk], hh0[kk], acc[v]);
                }
                if (t < SEQ - 1) {
#pragma unroll
                    for (int kk = 0; kk < 4; ++kk) {
                        bvh[v][kk] = *(const bf16x8*)(BhN + (size_t)v * MATSZ + kk * 32);
                        if (USE_BLO) bvl[v][kk] = *(const bf16x8*)(BlN + (size_t)v * MATSZ + kk * 32);
                    }
                }
            }
            int tokA = sm.a.toks[t * 16 + lr];
            f32x4 d0 = acc[0];
            d0 = (tokA == 1) ? acc[1] : d0;
            d0 = (tokA == 2) ? acc[2] : d0;
            d0 = (tokA == 3) ? acc[3] : d0;
            f32x4 h2_0 = hreg0 + d0;

            if ((t & 7) == 7) {            // renormalize every 8 steps
                float ss0 = h2_0[0]*h2_0[0] + h2_0[1]*h2_0[1] + h2_0[2]*h2_0[2] + h2_0[3]*h2_0[3];
                ss0 += __shfl_xor(ss0, 16);
                ss0 += __shfl_xor(ss0, 32);
                if (lq == 0) sm.a.partial[w][lr] = ss0;
                __syncthreads();
                if (tid < 16) {
                    float s2 = 0.f;
#pragma unroll
                    for (int w2 = 0; w2 < 8; ++w2) s2 += sm.a.partial[w2][tid];
                    sm.a.sinv[tid] = rsqrtf(s2);
                    sm.a.logn[tid] += 0.5f * logf(s2);
                }
                __syncthreads();
                h2_0 *= sm.a.sinv[lr];
            }
            hreg0 = h2_0;
            __syncthreads();               // all waves' h-frag reads complete
            {
                int c = lr;
                unsigned short q0 = f2bf(h2_0[0]), q1 = f2bf(h2_0[1]),
                               q2 = f2bf(h2_0[2]), q3 = f2bf(h2_0[3]);
                int c8w = w * 2 + (lq >> 1);
                int si  = xoff(c, c8w) + (lq & 1) * 4;
                *(ushort4*)&sm.a.hhi[si] = make_ushort4(q0, q1, q2, q3);
                *(ushort4*)&sm.a.hlo[si] =
                    make_ushort4(f2bf(h2_0[0] - bf2f(q0)), f2bf(h2_0[1] - bf2f(q1)),
                                 f2bf(h2_0[2] - bf2f(q2)), f2bf(h2_0[3] - bf2f(q3)));
            }
            __syncthreads();               // writes visible before next step's reads
        }
        f32x4 og = *(const f32x4*)(edge + BOND + w * 16 + lq * 4);
        {
            float ss = hreg0[0]*og[0] + hreg0[1]*og[1] + hreg0[2]*og[2] + hreg0[3]*og[3];
            ss += __shfl_xor(ss, 16);
            ss += __shfl_xor(ss, 32);
            if (lq == 0) sm.a.partial[w][lr] = ss;
        }
        __syncthreads();
        if (tid < 16) {
            float dot = 0.f;
#pragma unroll
            for (int w2 = 0; w2 < 8; ++w2) dot += sm.a.partial[w2][tid];
            logamp[b0 + tid] = 2.f * (logf(fabsf(dot)) + sm.a.logn[tid]);
        }
    }
}

// ---------------- finalize (unchanged) ----------------
__global__ __launch_bounds__(1024) void fin_kernel(const unsigned short* __restrict__ mws,
                                                   const float* __restrict__ logamp,
                                                   float* __restrict__ out) {
    __shared__ float red[1024];
    const int tid = threadIdx.x;
    const unsigned short* Sf = mws;
    const unsigned short* Rb = mws + MATSZ;
    float part = 0.f;
    for (int j = 0; j < 16; ++j) {
        int idx = tid + j * 1024;
        part += bf2f(Sf[idx]) * bf2f(Rb[idx]);
    }
    red[tid] = part;
    __syncthreads();
    for (int off = 512; off > 0; off >>= 1) {
        if (tid < off) red[tid] += red[tid + off];
        __syncthreads();
    }
    float lz = logf(red[0]) + 256.0f * 1.3862943611198906f;
    out[tid]        = logamp[tid]        - lz;
    out[tid + 1024] = logamp[tid + 1024] - lz;
}

extern "C" void kernel_launch(void* const* d_in, const int* in_sizes, int n_in,
                              void* d_out, int out_size, void* d_ws, size_t ws_size,
                              hipStream_t stream) {
    const int*   xdata = (const int*)d_in[0];
    const float* core  = (const float*)d_in[1];
    const float* edge  = (const float*)d_in[2];
    float* out = (float*)d_out;
    char* ws = (char*)d_ws;

    const size_t need_full  = OFF_BLO + SZ_MAT + SZ_TAIL;
    const size_t need_noblo = OFF_BLO + SZ_TAIL;
    const int use_blo = (ws_size >= need_full) ? 1 : 0;
    if (!use_blo && ws_size < need_noblo) return;

    unsigned short* abf  = (unsigned short*)(ws + OFF_ABF);
    unsigned short* atbf = (unsigned short*)(ws + OFF_ATBF);
    unsigned short* bhi  = (unsigned short*)(ws + OFF_BHI);
    unsigned short* blo  = (unsigned short*)(ws + (use_blo ? OFF_BLO : OFF_BHI));
    const size_t tail = use_blo ? (OFF_BLO + SZ_MAT) : OFF_BLO;
    unsigned short* mws  = (unsigned short*)(ws + tail);
    float* logamp = (float*)(ws + tail + SZ_MWS);

    convert_kernel<<<SEQ * INP, 256, 0, stream>>>(core, abf, atbf, bhi, blo, use_blo);
    if (use_blo)
        main_kernel<1><<<130, 512, 0, stream>>>(xdata, edge, abf, atbf, bhi, blo, mws, logamp);
    else
        main_kernel<0><<<130, 512, 0, stream>>>(xdata, edge, abf, atbf, bhi, blo, mws, logamp);
    fin_kernel<<<1, 1024, 0, stream>>>(mws, logamp, out);
}